// Round 1
// baseline (1093.557 us; speedup 1.0000x reference)
//
#include <hip/hip_runtime.h>
#include <hip/hip_bf16.h>
#include <cstdint>

// ---------------------------------------------------------------------------
// RNN_11828339933262: h = x @ w_in^T + b_in ; s_t = tanh(s_{t-1} @ W_n + h_t)
//                     y = rmsnorm(s) * norm_weight ; out = y @ w_out^T
// B=4 S=2048 D=2048 N_HEADS=32 HD=64.  All I/O f32; internal GEMMs bf16 MFMA.
// R4: scan — interleave TWO batch-chains of the same head per wave. The scan
// is latency-bound (495 cyc/step, ~5% VALUBusy): LDS write->broadcast-read
// round trip + tanh chain dominate. Two independent chains in one wave share
// the W registers (same head) and fill each other's stall bubbles; the DS
// pipe services both broadcasts back-to-back so the round-trip latency is
// paid once per step. Grid 128->64 blocks, ~2x on the scan dispatch.
// ---------------------------------------------------------------------------

typedef short bf16x8 __attribute__((ext_vector_type(8)));   // 8 bf16 = 4 VGPRs
typedef float f32x4 __attribute__((ext_vector_type(4)));
typedef float f32x2 __attribute__((ext_vector_type(2)));

#define GLD16(gp, lp)                                                          \
  __builtin_amdgcn_global_load_lds(                                            \
      (const __attribute__((address_space(1))) void*)(gp),                     \
      (__attribute__((address_space(3))) void*)(lp), 16, 0, 0)

// ---------------------------- f32 -> bf16 convert --------------------------
__global__ __launch_bounds__(256) void cvt_f32_bf16(
    const float* __restrict__ in, __hip_bfloat16* __restrict__ out, int n4) {
  int i = blockIdx.x * 256 + threadIdx.x;
  if (i >= n4) return;
  float4 v = ((const float4*)in)[i];
  __hip_bfloat16 a = __float2bfloat16(v.x);
  __hip_bfloat16 b = __float2bfloat16(v.y);
  __hip_bfloat16 c = __float2bfloat16(v.z);
  __hip_bfloat16 d = __float2bfloat16(v.w);
  ushort4 p;
  p.x = *(unsigned short*)&a; p.y = *(unsigned short*)&b;
  p.z = *(unsigned short*)&c; p.w = *(unsigned short*)&d;
  ((ushort4*)out)[i] = p;
}

// ------------------------------- NT GEMM ------------------------------------
__global__ __launch_bounds__(256) void gemm_nt(
    const __hip_bfloat16* __restrict__ A, const __hip_bfloat16* __restrict__ B,
    const float* __restrict__ bias, float* __restrict__ C,
    int M, int N, int K) {
  __shared__ __hip_bfloat16 As[128 * 32];
  __shared__ __hip_bfloat16 Bs[128 * 32];
  const int tid  = threadIdx.x;
  const int lane = tid & 63;
  const int wave = tid >> 6;
  const int wm = wave >> 1, wn = wave & 1;
  const long bm = (long)blockIdx.y * 128;
  const long bn = (long)blockIdx.x * 128;

  const int c0 = tid, c1 = tid + 256;
  const int r0 = c0 >> 2, k0 = (c0 & 3) * 8;
  const int r1 = c1 >> 2, k1 = (c1 & 3) * 8;
  __hip_bfloat16* lA0 = &As[(wave * 64) * 8];
  __hip_bfloat16* lA1 = &As[(256 + wave * 64) * 8];
  __hip_bfloat16* lB0 = &Bs[(wave * 64) * 8];
  __hip_bfloat16* lB1 = &Bs[(256 + wave * 64) * 8];
  const __hip_bfloat16* gA0 = A + (bm + r0) * (long)K + k0;
  const __hip_bfloat16* gA1 = A + (bm + r1) * (long)K + k1;
  const __hip_bfloat16* gB0 = B + (bn + r0) * (long)K + k0;
  const __hip_bfloat16* gB1 = B + (bn + r1) * (long)K + k1;

  const int fr = lane & 15;
  const int fk = (lane >> 4) * 8;

  f32x4 acc[4][4];
#pragma unroll
  for (int i = 0; i < 4; i++)
#pragma unroll
    for (int j = 0; j < 4; j++) acc[i][j] = {0.f, 0.f, 0.f, 0.f};

  for (int kt = 0; kt < K; kt += 32) {
    __syncthreads();
    GLD16(gA0 + kt, lA0);
    GLD16(gA1 + kt, lA1);
    GLD16(gB0 + kt, lB0);
    GLD16(gB1 + kt, lB1);
    __syncthreads();
    bf16x8 af[4], bfr[4];
#pragma unroll
    for (int t = 0; t < 4; t++)
      af[t] = *(const bf16x8*)&As[(wm * 64 + t * 16 + fr) * 32 + fk];
#pragma unroll
    for (int t = 0; t < 4; t++)
      bfr[t] = *(const bf16x8*)&Bs[(wn * 64 + t * 16 + fr) * 32 + fk];
#pragma unroll
    for (int i = 0; i < 4; i++)
#pragma unroll
      for (int j = 0; j < 4; j++)
        acc[i][j] = __builtin_amdgcn_mfma_f32_16x16x32_bf16(
            af[i], bfr[j], acc[i][j], 0, 0, 0);
  }

  const int cr = (lane >> 4) * 4;
  const int cc = lane & 15;
#pragma unroll
  for (int j = 0; j < 4; j++) {
    const long n = bn + wn * 64 + j * 16 + cc;
    const float bv = bias ? bias[n] : 0.0f;
#pragma unroll
    for (int i = 0; i < 4; i++) {
      const long m = bm + wm * 64 + i * 16 + cr;
#pragma unroll
      for (int r = 0; r < 4; r++)
        C[(m + r) * (long)N + n] = acc[i][j][r] + bv;
    }
  }
}

// ------------------------------- RNN scan -----------------------------------
// TWO chains (two batches of the SAME head) per 64-lane wave; lane k owns
// output k of both chains. W column packed as 32 f32x2 in VGPRs, shared by
// both chains. Each chain broadcasts its state through its own 64-float LDS
// region; single-wave block + in-order DS pipe -> no waitcnt between write
// and broadcast reads. The two chains' FMA/tanh work fills each other's
// LDS-round-trip latency; the DS pipe pipelines both broadcasts so the
// ~150-cycle round trip is paid once per step instead of once per chain.
__device__ __forceinline__ void pk_fma(f32x2& d, f32x2 a, f32x2 b) {
  asm("v_pk_fma_f32 %0, %1, %2, %0" : "+v"(d) : "v"(a), "v"(b));
}

__device__ __forceinline__ float tanh_fast(float z) {
  // tanh(z) = 1 - 2/(e^{2z}+1); e^{2z} = 2^(z * 2*log2(e)) — one mul + v_exp.
  float e = __builtin_amdgcn_exp2f(z * 2.8853900817779268f);
  return 1.0f - 2.0f * __builtin_amdgcn_rcpf(e + 1.0f);
}

__global__ __launch_bounds__(64) void scan_kernel(
    const float* __restrict__ Wst, float* __restrict__ h) {
  const int p  = blockIdx.x;        // 0..63
  const int n  = p & 31;            // head
  const int bp = p >> 5;            // batch pair: {0,1} or {2,3}
  const int lane = threadIdx.x;     // 0..63
  const float* Wn = Wst + n * 4096; // W[n][h][k], k contiguous
  f32x2 w2[32];
#pragma unroll
  for (int j = 0; j < 32; j++) {
    f32x2 t;
    t.x = Wn[(2 * j) * 64 + lane];
    t.y = Wn[(2 * j + 1) * 64 + lane];
    w2[j] = t;
  }

  __shared__ float s_lds[128];      // [0:64) chain A, [64:128) chain B

  // State fragments for the *upcoming* step; s_0 = 0 so start at zero
  // (each step writes s_lds before reading, so no priming write needed).
  float4 svA[16], svB[16];
#pragma unroll
  for (int i = 0; i < 16; i++) {
    svA[i] = make_float4(0.f, 0.f, 0.f, 0.f);
    svB[i] = make_float4(0.f, 0.f, 0.f, 0.f);
  }

  float* hpA = h + ((size_t)(2 * bp) * 2048) * 2048 + n * 64 + lane;
  float* hpB = hpA + (size_t)2048 * 2048;  // next batch, t-stride 2048 floats
  float xcA[8], xnA[8], xcB[8], xnB[8];
#pragma unroll
  for (int i = 0; i < 8; i++) {
    xcA[i] = hpA[(size_t)i * 2048];
    xcB[i] = hpB[(size_t)i * 2048];
  }

  for (int t0 = 0; t0 < 2048; t0 += 8) {
    if (t0 + 8 < 2048) {
#pragma unroll
      for (int i = 0; i < 8; i++) {
        xnA[i] = hpA[(size_t)(t0 + 8 + i) * 2048];
        xnB[i] = hpB[(size_t)(t0 + 8 + i) * 2048];
      }
    }
#pragma unroll
    for (int i = 0; i < 8; i++) {
      // dot(s_{t-1}, W[:,lane]) + x_t for both chains, FMAs interleaved so
      // either chain's work fills the other's lgkmcnt stalls.
      f32x2 aA[4], aB[4];
      aA[0].x = xcA[i]; aA[0].y = 0.f;
      aA[1] = aA[2] = aA[3] = f32x2{0.f, 0.f};
      aB[0].x = xcB[i]; aB[0].y = 0.f;
      aB[1] = aB[2] = aB[3] = f32x2{0.f, 0.f};
#pragma unroll
      for (int q = 0; q < 16; q++) {
        f32x2 loA; loA.x = svA[q].x; loA.y = svA[q].y;
        f32x2 hiA; hiA.x = svA[q].z; hiA.y = svA[q].w;
        f32x2 loB; loB.x = svB[q].x; loB.y = svB[q].y;
        f32x2 hiB; hiB.x = svB[q].z; hiB.y = svB[q].w;
        pk_fma(aA[(2 * q) & 3], loA, w2[2 * q]);
        pk_fma(aB[(2 * q) & 3], loB, w2[2 * q]);
        pk_fma(aA[(2 * q + 1) & 3], hiA, w2[2 * q + 1]);
        pk_fma(aB[(2 * q + 1) & 3], hiB, w2[2 * q + 1]);
      }
      f32x2 sA01 = aA[0] + aA[1];
      f32x2 sA23 = aA[2] + aA[3];
      f32x2 sAt = sA01 + sA23;
      float snA = tanh_fast(sAt.x + sAt.y);
      f32x2 sB01 = aB[0] + aB[1];
      f32x2 sB23 = aB[2] + aB[3];
      f32x2 sBt = sB01 + sB23;
      float snB = tanh_fast(sBt.x + sBt.y);
      // Broadcast s_t for step t+1: writes then immediately all 32 reads —
      // DS pipe is in-order per wave, no waitcnt needed between.
      s_lds[lane] = snA;
      s_lds[64 + lane] = snB;
#pragma unroll
      for (int q = 0; q < 16; q++) {
        svA[q] = ((const float4*)s_lds)[q];
        svB[q] = ((const float4*)s_lds)[16 + q];
      }
      hpA[(size_t)(t0 + i) * 2048] = snA;  // fire-and-forget, off the path
      hpB[(size_t)(t0 + i) * 2048] = snB;
    }
#pragma unroll
    for (int i = 0; i < 8; i++) { xcA[i] = xnA[i]; xcB[i] = xnB[i]; }
  }
}

// --------------------------- RMSNorm -> bf16 --------------------------------
__global__ __launch_bounds__(256) void rmsnorm_to_bf16(
    const float* __restrict__ Y, const float* __restrict__ g,
    __hip_bfloat16* __restrict__ O) {
  const long row = blockIdx.x;
  const float* yr = Y + row * 2048;
  const int tid = threadIdx.x;
  float4 v0 = ((const float4*)yr)[tid * 2];
  float4 v1 = ((const float4*)yr)[tid * 2 + 1];
  float ss = v0.x * v0.x + v0.y * v0.y + v0.z * v0.z + v0.w * v0.w +
             v1.x * v1.x + v1.y * v1.y + v1.z * v1.z + v1.w * v1.w;
#pragma unroll
  for (int off = 32; off > 0; off >>= 1) ss += __shfl_down(ss, off);
  __shared__ float red[4];
  if ((tid & 63) == 0) red[tid >> 6] = ss;
  __syncthreads();
  float inv = rsqrtf((red[0] + red[1] + red[2] + red[3]) * (1.0f / 2048.0f)
                     + 1e-6f);
  float4 g0 = ((const float4*)(g + tid * 8))[0];
  float4 g1 = ((const float4*)(g + tid * 8))[1];
  float ov[8] = {v0.x * inv * g0.x, v0.y * inv * g0.y,
                 v0.z * inv * g0.z, v0.w * inv * g0.w,
                 v1.x * inv * g1.x, v1.y * inv * g1.y,
                 v1.z * inv * g1.z, v1.w * inv * g1.w};
  ushort4 p0, p1;
  __hip_bfloat16 t;
  t = __float2bfloat16(ov[0]); p0.x = *(unsigned short*)&t;
  t = __float2bfloat16(ov[1]); p0.y = *(unsigned short*)&t;
  t = __float2bfloat16(ov[2]); p0.z = *(unsigned short*)&t;
  t = __float2bfloat16(ov[3]); p0.w = *(unsigned short*)&t;
  t = __float2bfloat16(ov[4]); p1.x = *(unsigned short*)&t;
  t = __float2bfloat16(ov[5]); p1.y = *(unsigned short*)&t;
  t = __float2bfloat16(ov[6]); p1.z = *(unsigned short*)&t;
  t = __float2bfloat16(ov[7]); p1.w = *(unsigned short*)&t;
  ushort4* op = (ushort4*)(O + row * 2048 + tid * 8);
  op[0] = p0;
  op[1] = p1;
}

// ------------------------------- launch -------------------------------------
extern "C" void kernel_launch(void* const* d_in, const int* in_sizes, int n_in,
                              void* d_out, int out_size, void* d_ws,
                              size_t ws_size, hipStream_t stream) {
  const float* x     = (const float*)d_in[0];  // (4,2048,2048)
  const float* w_in  = (const float*)d_in[1];  // (2048,2048)
  const float* b_in  = (const float*)d_in[2];  // (2048,)
  const float* w_st  = (const float*)d_in[3];  // (32,64,64)
  const float* nw    = (const float*)d_in[4];  // (2048,)
  const float* w_out = (const float*)d_in[5];  // (2048,2048)
  float* out = (float*)d_out;

  char* ws = (char*)d_ws;
  __hip_bfloat16* x_bf  = (__hip_bfloat16*)(ws);              // 33,554,432 B
  __hip_bfloat16* wi_bf = (__hip_bfloat16*)(ws + 33554432);   //  8,388,608 B
  __hip_bfloat16* wo_bf = (__hip_bfloat16*)(ws + 41943040);   //  8,388,608 B
  float* h              = (float*)(ws + 50331648);            // 67,108,864 B
  // x_bf buffer is reused for the rmsnorm'ed bf16 states (same size).

  cvt_f32_bf16<<<16384, 256, 0, stream>>>(x, x_bf, 4194304);
  cvt_f32_bf16<<<4096, 256, 0, stream>>>(w_in, wi_bf, 1048576);
  cvt_f32_bf16<<<4096, 256, 0, stream>>>(w_out, wo_bf, 1048576);

  // h = x @ w_in^T + b_in   (M=8192, N=2048, K=2048)
  gemm_nt<<<dim3(16, 64), 256, 0, stream>>>(x_bf, wi_bf, b_in, h,
                                            8192, 2048, 2048);
  // in-place tanh recurrence: 2 batch-chains of one head per wave
  scan_kernel<<<64, 64, 0, stream>>>(w_st, h);
  // rmsnorm + cast to bf16 (into x_bf buffer)
  rmsnorm_to_bf16<<<8192, 256, 0, stream>>>(h, nw, x_bf);
  // out = y_norm @ w_out^T
  gemm_nt<<<dim3(16, 64), 256, 0, stream>>>(x_bf, wo_bf, nullptr, out,
                                            8192, 2048, 2048);
}

// Round 3
// 760.755 us; speedup vs baseline: 1.4375x; 1.4375x over previous
//
#include <hip/hip_runtime.h>
#include <hip/hip_bf16.h>
#include <cstdint>

// ---------------------------------------------------------------------------
// RNN_11828339933262: h = x @ w_in^T + b_in ; s_t = tanh(s_{t-1} @ W_n + h_t)
//                     y = rmsnorm(s) * norm_weight ; out = y @ w_out^T
// B=4 S=2048 D=2048 N_HEADS=32 HD=64.  All I/O f32; internal GEMMs bf16 MFMA.
// R6: scan — R5 resubmit with assembler-safe dot product. The scan is
// latency-bound; R4's 2-chain experiment proved DS reads + VALU issue fully
// SERIALIZE on the step path (12 cyc/ds_read_b128, 4 cyc/pk_fma). Shrink the
// serial path: state broadcast in FP16 (8 ds_read_b128 instead of 16) and
// matvec via v_dot2_f32_f16 (__builtin_amdgcn_fdot2, gfx906+; full-rate
// 2-cyc, f32 accumulate). Predicted step 495 -> ~330 cyc. State is in [-1,1]
// post-tanh so fp16 (ulp 2^-11) is MORE accurate than bf16 here; x-term and
// accumulation stay f32; recurrence is contractive so rounding cannot grow.
// ---------------------------------------------------------------------------

typedef short bf16x8 __attribute__((ext_vector_type(8)));   // 8 bf16 = 4 VGPRs
typedef float f32x4 __attribute__((ext_vector_type(4)));
typedef _Float16 f16x2 __attribute__((ext_vector_type(2)));

#define GLD16(gp, lp)                                                          \
  __builtin_amdgcn_global_load_lds(                                            \
      (const __attribute__((address_space(1))) void*)(gp),                     \
      (__attribute__((address_space(3))) void*)(lp), 16, 0, 0)

// ---------------------------- f32 -> bf16 convert --------------------------
__global__ __launch_bounds__(256) void cvt_f32_bf16(
    const float* __restrict__ in, __hip_bfloat16* __restrict__ out, int n4) {
  int i = blockIdx.x * 256 + threadIdx.x;
  if (i >= n4) return;
  float4 v = ((const float4*)in)[i];
  __hip_bfloat16 a = __float2bfloat16(v.x);
  __hip_bfloat16 b = __float2bfloat16(v.y);
  __hip_bfloat16 c = __float2bfloat16(v.z);
  __hip_bfloat16 d = __float2bfloat16(v.w);
  ushort4 p;
  p.x = *(unsigned short*)&a; p.y = *(unsigned short*)&b;
  p.z = *(unsigned short*)&c; p.w = *(unsigned short*)&d;
  ((ushort4*)out)[i] = p;
}

// ------------------------------- NT GEMM ------------------------------------
__global__ __launch_bounds__(256) void gemm_nt(
    const __hip_bfloat16* __restrict__ A, const __hip_bfloat16* __restrict__ B,
    const float* __restrict__ bias, float* __restrict__ C,
    int M, int N, int K) {
  __shared__ __hip_bfloat16 As[128 * 32];
  __shared__ __hip_bfloat16 Bs[128 * 32];
  const int tid  = threadIdx.x;
  const int lane = tid & 63;
  const int wave = tid >> 6;
  const int wm = wave >> 1, wn = wave & 1;
  const long bm = (long)blockIdx.y * 128;
  const long bn = (long)blockIdx.x * 128;

  const int c0 = tid, c1 = tid + 256;
  const int r0 = c0 >> 2, k0 = (c0 & 3) * 8;
  const int r1 = c1 >> 2, k1 = (c1 & 3) * 8;
  __hip_bfloat16* lA0 = &As[(wave * 64) * 8];
  __hip_bfloat16* lA1 = &As[(256 + wave * 64) * 8];
  __hip_bfloat16* lB0 = &Bs[(wave * 64) * 8];
  __hip_bfloat16* lB1 = &Bs[(256 + wave * 64) * 8];
  const __hip_bfloat16* gA0 = A + (bm + r0) * (long)K + k0;
  const __hip_bfloat16* gA1 = A + (bm + r1) * (long)K + k1;
  const __hip_bfloat16* gB0 = B + (bn + r0) * (long)K + k0;
  const __hip_bfloat16* gB1 = B + (bn + r1) * (long)K + k1;

  const int fr = lane & 15;
  const int fk = (lane >> 4) * 8;

  f32x4 acc[4][4];
#pragma unroll
  for (int i = 0; i < 4; i++)
#pragma unroll
    for (int j = 0; j < 4; j++) acc[i][j] = {0.f, 0.f, 0.f, 0.f};

  for (int kt = 0; kt < K; kt += 32) {
    __syncthreads();
    GLD16(gA0 + kt, lA0);
    GLD16(gA1 + kt, lA1);
    GLD16(gB0 + kt, lB0);
    GLD16(gB1 + kt, lB1);
    __syncthreads();
    bf16x8 af[4], bfr[4];
#pragma unroll
    for (int t = 0; t < 4; t++)
      af[t] = *(const bf16x8*)&As[(wm * 64 + t * 16 + fr) * 32 + fk];
#pragma unroll
    for (int t = 0; t < 4; t++)
      bfr[t] = *(const bf16x8*)&Bs[(wn * 64 + t * 16 + fr) * 32 + fk];
#pragma unroll
    for (int i = 0; i < 4; i++)
#pragma unroll
      for (int j = 0; j < 4; j++)
        acc[i][j] = __builtin_amdgcn_mfma_f32_16x16x32_bf16(
            af[i], bfr[j], acc[i][j], 0, 0, 0);
  }

  const int cr = (lane >> 4) * 4;
  const int cc = lane & 15;
#pragma unroll
  for (int j = 0; j < 4; j++) {
    const long n = bn + wn * 64 + j * 16 + cc;
    const float bv = bias ? bias[n] : 0.0f;
#pragma unroll
    for (int i = 0; i < 4; i++) {
      const long m = bm + wm * 64 + i * 16 + cr;
#pragma unroll
      for (int r = 0; r < 4; r++)
        C[(m + r) * (long)N + n] = acc[i][j][r] + bv;
    }
  }
}

// ------------------------------- RNN scan -----------------------------------
// One wave per (batch, head) chain; lane k owns output k. State broadcast in
// FP16 through a 128-byte LDS buffer: lane writes its new value (b16), then
// all lanes read the full state with 8 ds_read_b128 (same-address broadcast,
// conflict-free). Matvec: 32 v_dot2_f32_f16 (2 fp16 MACs each, f32 acc)
// against pre-packed fp16 weight pairs held in VGPRs. Single-wave block +
// in-order DS pipe -> no waitcnt between the write and the broadcast reads;
// compiler gates each dot2 on its read with fine-grained lgkmcnt.
__device__ __forceinline__ float tanh_fast(float z) {
  // tanh(z) = 1 - 2/(e^{2z}+1); e^{2z} = 2^(z * 2*log2(e)) — one mul + v_exp.
  float e = __builtin_amdgcn_exp2f(z * 2.8853900817779268f);
  return 1.0f - 2.0f * __builtin_amdgcn_rcpf(e + 1.0f);
}

__global__ __launch_bounds__(64) void scan_kernel(
    const float* __restrict__ Wst, float* __restrict__ h) {
  const int b = blockIdx.x >> 5;    // 0..3
  const int n = blockIdx.x & 31;    // 0..31
  const int lane = threadIdx.x;     // 0..63
  const float* Wn = Wst + n * 4096; // W[n][h][k], k contiguous

  // Packed fp16 weight pairs: w2[j] = {W[2j][lane], W[2j+1][lane]}.
  f16x2 w2[32];
#pragma unroll
  for (int j = 0; j < 32; j++) {
    f16x2 t;
    t.x = (_Float16)Wn[(2 * j) * 64 + lane];
    t.y = (_Float16)Wn[(2 * j + 1) * 64 + lane];
    w2[j] = t;
  }

  __shared__ alignas(16) unsigned short s_h[64];  // 128 B fp16 state

  // Packed state dwords for the upcoming step; s_0 = 0 (fp16 zero = 0x0000),
  // so start from zero registers (first write precedes first read).
  int4 sv[8];
#pragma unroll
  for (int q = 0; q < 8; q++) sv[q] = make_int4(0, 0, 0, 0);

  float* hp = h + ((size_t)b * 2048) * 2048 + n * 64 + lane;  // t-stride 2048
  float xcur[8], xnxt[8];
#pragma unroll
  for (int i = 0; i < 8; i++) xcur[i] = hp[(size_t)i * 2048];

  for (int t0 = 0; t0 < 2048; t0 += 8) {
    if (t0 + 8 < 2048) {
#pragma unroll
      for (int i = 0; i < 8; i++)
        xnxt[i] = hp[(size_t)(t0 + 8 + i) * 2048];
    }
#pragma unroll
    for (int i = 0; i < 8; i++) {
      // z = dot(s_{t-1}, W[:,lane]) + x_t ; consumed in read-return order so
      // the compiler's progressive lgkmcnt lets dot2s start as reads land.
      float a0 = xcur[i], a1 = 0.f, a2 = 0.f, a3 = 0.f;
#pragma unroll
      for (int q = 0; q < 8; q++) {
        a0 = __builtin_amdgcn_fdot2(__builtin_bit_cast(f16x2, sv[q].x),
                                    w2[4 * q + 0], a0, false);
        a1 = __builtin_amdgcn_fdot2(__builtin_bit_cast(f16x2, sv[q].y),
                                    w2[4 * q + 1], a1, false);
        a2 = __builtin_amdgcn_fdot2(__builtin_bit_cast(f16x2, sv[q].z),
                                    w2[4 * q + 2], a2, false);
        a3 = __builtin_amdgcn_fdot2(__builtin_bit_cast(f16x2, sv[q].w),
                                    w2[4 * q + 3], a3, false);
      }
      float z = (a0 + a1) + (a2 + a3);
      float sn = tanh_fast(z);
      // Broadcast s_t for step t+1: one b16 write then 8 b128 broadcast
      // reads — DS pipe is in-order per wave, no waitcnt needed between.
      _Float16 sh = (_Float16)sn;
      s_h[lane] = __builtin_bit_cast(unsigned short, sh);
#pragma unroll
      for (int q = 0; q < 8; q++) sv[q] = ((const int4*)s_h)[q];
      hp[(size_t)(t0 + i) * 2048] = sn;   // fire-and-forget, off the path
    }
#pragma unroll
    for (int i = 0; i < 8; i++) xcur[i] = xnxt[i];
  }
}

// --------------------------- RMSNorm -> bf16 --------------------------------
__global__ __launch_bounds__(256) void rmsnorm_to_bf16(
    const float* __restrict__ Y, const float* __restrict__ g,
    __hip_bfloat16* __restrict__ O) {
  const long row = blockIdx.x;
  const float* yr = Y + row * 2048;
  const int tid = threadIdx.x;
  float4 v0 = ((const float4*)yr)[tid * 2];
  float4 v1 = ((const float4*)yr)[tid * 2 + 1];
  float ss = v0.x * v0.x + v0.y * v0.y + v0.z * v0.z + v0.w * v0.w +
             v1.x * v1.x + v1.y * v1.y + v1.z * v1.z + v1.w * v1.w;
#pragma unroll
  for (int off = 32; off > 0; off >>= 1) ss += __shfl_down(ss, off);
  __shared__ float red[4];
  if ((tid & 63) == 0) red[tid >> 6] = ss;
  __syncthreads();
  float inv = rsqrtf((red[0] + red[1] + red[2] + red[3]) * (1.0f / 2048.0f)
                     + 1e-6f);
  float4 g0 = ((const float4*)(g + tid * 8))[0];
  float4 g1 = ((const float4*)(g + tid * 8))[1];
  float ov[8] = {v0.x * inv * g0.x, v0.y * inv * g0.y,
                 v0.z * inv * g0.z, v0.w * inv * g0.w,
                 v1.x * inv * g1.x, v1.y * inv * g1.y,
                 v1.z * inv * g1.z, v1.w * inv * g1.w};
  ushort4 p0, p1;
  __hip_bfloat16 t;
  t = __float2bfloat16(ov[0]); p0.x = *(unsigned short*)&t;
  t = __float2bfloat16(ov[1]); p0.y = *(unsigned short*)&t;
  t = __float2bfloat16(ov[2]); p0.z = *(unsigned short*)&t;
  t = __float2bfloat16(ov[3]); p0.w = *(unsigned short*)&t;
  t = __float2bfloat16(ov[4]); p1.x = *(unsigned short*)&t;
  t = __float2bfloat16(ov[5]); p1.y = *(unsigned short*)&t;
  t = __float2bfloat16(ov[6]); p1.z = *(unsigned short*)&t;
  t = __float2bfloat16(ov[7]); p1.w = *(unsigned short*)&t;
  ushort4* op = (ushort4*)(O + row * 2048 + tid * 8);
  op[0] = p0;
  op[1] = p1;
}

// ------------------------------- launch -------------------------------------
extern "C" void kernel_launch(void* const* d_in, const int* in_sizes, int n_in,
                              void* d_out, int out_size, void* d_ws,
                              size_t ws_size, hipStream_t stream) {
  const float* x     = (const float*)d_in[0];  // (4,2048,2048)
  const float* w_in  = (const float*)d_in[1];  // (2048,2048)
  const float* b_in  = (const float*)d_in[2];  // (2048,)
  const float* w_st  = (const float*)d_in[3];  // (32,64,64)
  const float* nw    = (const float*)d_in[4];  // (2048,)
  const float* w_out = (const float*)d_in[5];  // (2048,2048)
  float* out = (float*)d_out;

  char* ws = (char*)d_ws;
  __hip_bfloat16* x_bf  = (__hip_bfloat16*)(ws);              // 33,554,432 B
  __hip_bfloat16* wi_bf = (__hip_bfloat16*)(ws + 33554432);   //  8,388,608 B
  __hip_bfloat16* wo_bf = (__hip_bfloat16*)(ws + 41943040);   //  8,388,608 B
  float* h              = (float*)(ws + 50331648);            // 67,108,864 B
  // x_bf buffer is reused for the rmsnorm'ed bf16 states (same size).

  cvt_f32_bf16<<<16384, 256, 0, stream>>>(x, x_bf, 4194304);
  cvt_f32_bf16<<<4096, 256, 0, stream>>>(w_in, wi_bf, 1048576);
  cvt_f32_bf16<<<4096, 256, 0, stream>>>(w_out, wo_bf, 1048576);

  // h = x @ w_in^T + b_in   (M=8192, N=2048, K=2048)
  gemm_nt<<<dim3(16, 64), 256, 0, stream>>>(x_bf, wi_bf, b_in, h,
                                            8192, 2048, 2048);
  // in-place tanh recurrence per (batch, head)
  scan_kernel<<<128, 64, 0, stream>>>(w_st, h);
  // rmsnorm + cast to bf16 (into x_bf buffer)
  rmsnorm_to_bf16<<<8192, 256, 0, stream>>>(h, nw, x_bf);
  // out = y_norm @ w_out^T
  gemm_nt<<<dim3(16, 64), 256, 0, stream>>>(x_bf, wo_bf, nullptr, out,
                                            8192, 2048, 2048);
}